// Round 2
// baseline (192.212 us; speedup 1.0000x reference)
//
#include <hip/hip_runtime.h>
#include <hip/hip_bf16.h>

typedef short bf16x8 __attribute__((ext_vector_type(8)));
typedef float f32x4  __attribute__((ext_vector_type(4)));

#define NROWS 16384
#define EMB   256
#define FFN   1024

__device__ __forceinline__ unsigned short f2bf(float f) {
    unsigned int u = __builtin_bit_cast(unsigned int, f);
    u = (u + 0x7FFFu + ((u >> 16) & 1u)) >> 16;
    return (unsigned short)u;
}

// ---------------- K0: convert w2 (256x1024 f32) -> bf16 ----------------
__global__ __launch_bounds__(256) void cvt_w2_kernel(const float* __restrict__ w2,
                                                     unsigned short* __restrict__ w2b) {
    int i = blockIdx.x * 256 + threadIdx.x;          // 65536 threads, 4 elems each
    float4 v = reinterpret_cast<const float4*>(w2)[i];
    ushort4 o;
    o.x = f2bf(v.x); o.y = f2bf(v.y); o.z = f2bf(v.z); o.w = f2bf(v.w);
    reinterpret_cast<ushort4*>(w2b)[i] = o;
}

// ---------------- K1: quantum circuit -> meas (16384 x 10 f32) ----------------
// One wave per row. State: 1024 complex amps, 16 per lane (j = lane*16 + r).
// Circuit rewritten CNOT-free: masked rotations + sign-mask measurement.
__global__ __launch_bounds__(256) void quantum_kernel(const float* __restrict__ x,
                                                      const float* __restrict__ qp,
                                                      float* __restrict__ meas) {
    const int lane = threadIdx.x & 63;
    const int row  = (blockIdx.x << 2) + (threadIdx.x >> 6);

    // theta_w = x[row, w] + q_params[0, w]   (RX on same wire compose additively)
    float ang = 0.f;
    if (lane < 10) ang = x[row * EMB + lane] + qp[lane];

    float c[10], s[10];
#pragma unroll
    for (int w = 0; w < 10; ++w) {
        float h = 0.5f * __shfl(ang, w, 64);
        __sincosf(h, &s[w], &c[w]);
    }

    // product state R(theta)|0>: amp[j] = (prod magnitudes) * (-i)^popcount(j)
    // bit p of j <-> wire 9-p ; lane bits are j[9:4], r bits are j[3:0]
    float g = 1.f;
#pragma unroll
    for (int b = 0; b < 6; ++b)
        g *= ((lane >> b) & 1) ? s[5 - b] : c[5 - b];

    const int lpc = __popc(lane);
    float re[16], im[16];
#pragma unroll
    for (int r = 0; r < 16; ++r) {
        float m = g;
        m *= (r & 1) ? s[9] : c[9];
        m *= (r & 2) ? s[8] : c[8];
        m *= (r & 4) ? s[7] : c[7];
        m *= (r & 8) ? s[6] : c[6];
        const int pc = (lpc + __builtin_popcount(r)) & 3;
        re[r] = (pc == 0) ? m : ((pc == 2) ? -m : 0.f);
        im[r] = (pc == 1) ? -m : ((pc == 3) ? m : 0.f);
    }

    // layer-1 RX conjugated through first CNOT ring: masks L*e_p
    // wire w -> mask: {0x300,0x180,0x0C0,0x060,0x030,0x018,0x00C,0x006,0x003,0x301}
    const int LMv[10] = {0x30,0x18,0x0C,0x06,0x03,0x01,0x00,0x00,0x00,0x30};
    const int RMv[10] = {0x00,0x00,0x00,0x00,0x00,0x08,0x0C,0x06,0x03,0x01};

#pragma unroll
    for (int w = 0; w < 10; ++w) {
        float sa, ca;
        __sincosf(0.5f * qp[10 + w], &sa, &ca);   // q_params[1, w] (wave-uniform)
        const int lm = LMv[w], rm = RMv[w];
        float bre[16], bim[16];                   // snapshot of partner amplitudes
#pragma unroll
        for (int r = 0; r < 16; ++r) {
            float tr = re[r ^ rm];
            float ti = im[r ^ rm];
            if (lm) { tr = __shfl_xor(tr, lm, 64); ti = __shfl_xor(ti, lm, 64); }
            bre[r] = tr; bim[r] = ti;
        }
#pragma unroll
        for (int r = 0; r < 16; ++r) {            // phi' = c*phi - i*s*phi_partner
            float nr = ca * re[r] + sa * bim[r];
            float ni = ca * im[r] - sa * bre[r];
            re[r] = nr; im[r] = ni;
        }
    }

    float p[16];
#pragma unroll
    for (int r = 0; r < 16; ++r) p[r] = re[r] * re[r] + im[r] * im[r];

    // measurement sign masks u_k = rows of (L^2)^-1 (final perm absorbed):
    // w0..w9: 0x355,0x2FF,0x17F,0x2BF,0x15F,0x2AF,0x157,0x2AB,0x155,0x2AA
    float S5 = 0, S7 = 0, SA = 0, SB = 0, SF = 0;   // intra-lane signed sums
#pragma unroll
    for (int r = 0; r < 16; ++r) {
        S5 += (__builtin_popcount(r & 0x5) & 1) ? -p[r] : p[r];
        S7 += (__builtin_popcount(r & 0x7) & 1) ? -p[r] : p[r];
        SA += (__builtin_popcount(r & 0xA) & 1) ? -p[r] : p[r];
        SB += (__builtin_popcount(r & 0xB) & 1) ? -p[r] : p[r];
        SF += (__builtin_popcount(r & 0xF) & 1) ? -p[r] : p[r];
    }

    const int ULv[10] = {0x35,0x2F,0x17,0x2B,0x15,0x2A,0x15,0x2A,0x15,0x2A};
    float Sr[10] = {S5, SF, SF, SF, SF, SF, S7, SB, S5, SA};
    float v[10];
#pragma unroll
    for (int k = 0; k < 10; ++k) {
        float sg = (__popc(lane & ULv[k]) & 1) ? -1.f : 1.f;
        v[k] = sg * Sr[k];
#pragma unroll
        for (int m = 1; m < 64; m <<= 1) v[k] += __shfl_xor(v[k], m, 64);
    }
    float outv = 0.f;
#pragma unroll
    for (int k = 0; k < 10; ++k) outv = (lane == k) ? v[k] : outv;
    if (lane < 10) meas[row * 10 + lane] = outv;
}

// ---------------- K3: fused FFN: h = relu(meas@w1T+b1) [f32], out = h@w2T+b2 [MFMA bf16]
__global__ __launch_bounds__(256) void ffn_kernel(const float* __restrict__ meas,
                                                  const float* __restrict__ w1,
                                                  const float* __restrict__ b1,
                                                  const unsigned short* __restrict__ w2b,
                                                  const float* __restrict__ b2,
                                                  float* __restrict__ out) {
    __shared__ unsigned short hT[32 * 1024];   // 64KB, XOR-swizzled 16B blocks
    __shared__ float measT[32][10];

    const int tid  = threadIdx.x;
    const int row0 = blockIdx.x << 5;          // 32 rows per block

    for (int i = tid; i < 320; i += 256)
        measT[i / 10][i % 10] = meas[row0 * 10 + i];
    __syncthreads();

    // ---- Phase A: h tile (32 x 1024) in f32, stored bf16 to LDS
    {
        const int fb    = tid & 127;           // 16B block (8 f-values) within row
        const int rbase = (tid >> 7) << 4;     // 0 or 16
        const int f0    = fb << 3;

        float w1r[80];
#pragma unroll
        for (int q = 0; q < 80; ++q) w1r[q] = w1[f0 * 10 + q];
        float b1r[8];
#pragma unroll
        for (int j = 0; j < 8; ++j) b1r[j] = b1[f0 + j];

#pragma unroll 1
        for (int r = 0; r < 16; ++r) {
            const int rw = rbase + r;
            float mk[10];
#pragma unroll
            for (int k = 0; k < 10; ++k) mk[k] = measT[rw][k];
            float hv[8];
#pragma unroll
            for (int j = 0; j < 8; ++j) {
                float a = b1r[j];
#pragma unroll
                for (int k = 0; k < 10; ++k) a = fmaf(mk[k], w1r[j * 10 + k], a);
                hv[j] = fmaxf(a, 0.f);
            }
            uint4 pk;
            pk.x = f2bf(hv[0]) | ((unsigned)f2bf(hv[1]) << 16);
            pk.y = f2bf(hv[2]) | ((unsigned)f2bf(hv[3]) << 16);
            pk.z = f2bf(hv[4]) | ((unsigned)f2bf(hv[5]) << 16);
            pk.w = f2bf(hv[6]) | ((unsigned)f2bf(hv[7]) << 16);
            const int sfb = fb ^ (rw & 7);     // bank swizzle
            *reinterpret_cast<uint4*>(&hT[(rw * 128 + sfb) * 8]) = pk;
        }
    }
    __syncthreads();

    // ---- Phase B: out tile = h(32x1024) @ w2b^T(1024x256) via MFMA 16x16x32
    const int lane  = tid & 63;
    const int wave  = tid >> 6;
    const int wm    = wave >> 1;               // row half (16 rows)
    const int wn    = wave & 1;                // col half (128 cols)
    const int arow  = (wm << 4) + (lane & 15);
    const int kgrp  = lane >> 4;
    const int ncol0 = wn << 7;

    f32x4 acc[8];
#pragma unroll
    for (int j = 0; j < 8; ++j) acc[j] = f32x4{0.f, 0.f, 0.f, 0.f};

#pragma unroll 2
    for (int ks = 0; ks < 32; ++ks) {
        const int k0 = ks << 5;
        const int kb = (k0 >> 3) + kgrp;       // 16B-block along K
        bf16x8 a = *reinterpret_cast<const bf16x8*>(
            &hT[(arow * 128 + (kb ^ (arow & 7))) * 8]);
#pragma unroll
        for (int j = 0; j < 8; ++j) {
            const int col = ncol0 + (j << 4) + (lane & 15);
            bf16x8 b = *reinterpret_cast<const bf16x8*>(
                &w2b[col * 1024 + k0 + (kgrp << 3)]);
            acc[j] = __builtin_amdgcn_mfma_f32_16x16x32_bf16(a, b, acc[j], 0, 0, 0);
        }
    }

    const int orow = row0 + (wm << 4) + (kgrp << 2);
#pragma unroll
    for (int j = 0; j < 8; ++j) {
        const int col  = ncol0 + (j << 4) + (lane & 15);
        const float bb = b2[col];
#pragma unroll
        for (int i = 0; i < 4; ++i)
            out[(orow + i) * EMB + col] = acc[j][i] + bb;
    }
}

extern "C" void kernel_launch(void* const* d_in, const int* in_sizes, int n_in,
                              void* d_out, int out_size, void* d_ws, size_t ws_size,
                              hipStream_t stream) {
    const float* x  = (const float*)d_in[0];
    const float* qp = (const float*)d_in[1];
    const float* w1 = (const float*)d_in[2];
    const float* b1 = (const float*)d_in[3];
    const float* w2 = (const float*)d_in[4];
    const float* b2 = (const float*)d_in[5];
    float* out = (float*)d_out;

    float*          meas = (float*)d_ws;                          // 655,360 B
    unsigned short* w2b  = (unsigned short*)((char*)d_ws + (1 << 20)); // 524,288 B

    hipLaunchKernelGGL(cvt_w2_kernel, dim3(256), dim3(256), 0, stream, w2, w2b);
    hipLaunchKernelGGL(quantum_kernel, dim3(NROWS / 4), dim3(256), 0, stream, x, qp, meas);
    hipLaunchKernelGGL(ffn_kernel, dim3(NROWS / 32), dim3(256), 0, stream,
                       meas, w1, b1, w2b, b2, out);
}

// Round 5
// 120.788 us; speedup vs baseline: 1.5913x; 1.5913x over previous
//
#include <hip/hip_runtime.h>
#include <hip/hip_bf16.h>

typedef short bf16x8 __attribute__((ext_vector_type(8)));
typedef float f32x4  __attribute__((ext_vector_type(4)));

#define NROWS 16384
#define EMB   256

__device__ __forceinline__ unsigned short f2bf(float f) {
    unsigned int u = __builtin_bit_cast(unsigned int, f);
    u = (u + 0x7FFFu + ((u >> 16) & 1u)) >> 16;
    return (unsigned short)u;
}
__device__ __forceinline__ float bf2f(unsigned short h) {
    return __builtin_bit_cast(float, ((unsigned int)h) << 16);
}

// CNOT-conjugated rotation masks m_w and measurement sign-masks u_k (j-bit space)
__device__ __constant__ int d_m[10] = {0x300,0x180,0x0C0,0x060,0x030,0x018,0x00C,0x006,0x003,0x301};
__device__ __constant__ int d_u[10] = {0x355,0x2FF,0x17F,0x2BF,0x15F,0x2AF,0x157,0x2AB,0x155,0x2AA};
// anticommuting sets W_k = {w : popc(u_k & m_w) odd}
__device__ __constant__ int d_W[10] = {0x3FE,0x003,0x007,0x00F,0x01F,0x03F,0x07F,0x0FF,0x1FF,0x3FF};
// dense-table offsets: sizes 2^popc(u_k) = {64,512,256,256,128,128,64,64,32,32}
__device__ __constant__ int d_off[10] = {0,64,576,832,1088,1216,1344,1408,1472,1504};

// ---------------- K0: w2 (256x1024 f32) -> bf16 ----------------
__global__ __launch_bounds__(256) void cvt_w2_kernel(const float* __restrict__ w2,
                                                     unsigned short* __restrict__ w2b) {
    int i = blockIdx.x * 256 + threadIdx.x;
    float4 v = reinterpret_cast<const float4*>(w2)[i];
    ushort4 o;
    o.x = f2bf(v.x); o.y = f2bf(v.y); o.z = f2bf(v.z); o.w = f2bf(v.w);
    reinterpret_cast<ushort4*>(w2b)[i] = o;
}

// ---------------- K1: Pauli-path coefficient tables (1536 f32) ----------------
__global__ __launch_bounds__(1024) void qtab_kernel(const float* __restrict__ qp,
                                                    float* __restrict__ tabs) {
    __shared__ float T[1536];
    __shared__ float SA[10], CA[10];
    int t = threadIdx.x;
    if (t < 10) { float s, c; __sincosf(qp[10 + t], &s, &c); SA[t] = s; CA[t] = c; }
    for (int i = t; i < 1536; i += 1024) T[i] = 0.f;
    __syncthreads();
    for (int k = 0; k < 10; ++k) {
        int W = d_W[k], u = d_u[k], nW = __popc(W);
        for (int s = t; s < (1 << nW); s += 1024) {
            float coef = 1.f; int a = 0, cnt = 0, sb = s;
            for (int w = 0; w < 10; ++w) {
                if (!((W >> w) & 1)) continue;
                if (sb & 1) { coef *= SA[w]; a ^= d_m[w]; ++cnt; }
                else        { coef *= CA[w]; }
                sb >>= 1;
            }
            if (a & ~u) continue;                  // X-factor survives -> expectation 0
            if (((cnt + __popc(a)) >> 1) & 1) coef = -coef;   // i^{|S|+|a|}, sum always even
            int idx = 0, b = 0;                    // pext(a, u), LSB-first
            for (int p = 0; p < 10; ++p) if ((u >> p) & 1) {
                if ((a >> p) & 1) idx |= 1 << b;
                ++b;
            }
            atomicAdd(&T[d_off[k] + idx], coef);
        }
    }
    __syncthreads();
    for (int i = t; i < 1536; i += 1024) tabs[i] = T[i];
}

// ---------------- K2: per-row multilinear fold -> meas (16384 x 10 f32) ----------------
constexpr int bitpos(unsigned u, int t) {
    for (int p = 0; p < 32; ++p) if ((u >> p) & 1) { if (t == 0) return p; --t; }
    return 0;
}
template<unsigned U, int P>
struct Fold {
    static __device__ __forceinline__ float ev(const float*& tp, const float* cc, const float* ss) {
        float L = Fold<U, P - 1>::ev(tp, cc, ss);
        float R = Fold<U, P - 1>::ev(tp, cc, ss);
        constexpr int p = bitpos(U, P - 1);
        return cc[9 - p] * L + ss[9 - p] * R;   // bit p of j <-> wire 9-p
    }
};
template<unsigned U>
struct Fold<U, 0> {
    static __device__ __forceinline__ float ev(const float*& tp, const float*, const float*) {
        return *tp++;
    }
};

__global__ __launch_bounds__(128) void qpoly_kernel(const float* __restrict__ x,
                                                    const float* __restrict__ qp,
                                                    const float* __restrict__ tabs,
                                                    float* __restrict__ meas) {
    int t = threadIdx.x;
    int row = blockIdx.x * 64 + (t & 63);
    float cc[10], ss[10];
#pragma unroll
    for (int w = 0; w < 10; ++w) {
        float th = x[row * EMB + w] + qp[w];      // layer-0 params fold into data angles
        __sincosf(th, &ss[w], &cc[w]);            // FULL angle (expectations)
    }
    float* mo = meas + row * 10;
    if (t < 64) {   // half A: k in {1,6,7,8,9}
        const float* tp = tabs + 64;   mo[1] = Fold<0x2FF, 9>::ev(tp, cc, ss);
        tp = tabs + 1344;              mo[6] = Fold<0x157, 6>::ev(tp, cc, ss);
        tp = tabs + 1408;              mo[7] = Fold<0x2AB, 6>::ev(tp, cc, ss);
        tp = tabs + 1472;              mo[8] = Fold<0x155, 5>::ev(tp, cc, ss);
        tp = tabs + 1504;              mo[9] = Fold<0x2AA, 5>::ev(tp, cc, ss);
    } else {        // half B: k in {0,2,3,4,5}
        const float* tp = tabs;        mo[0] = Fold<0x355, 6>::ev(tp, cc, ss);
        tp = tabs + 576;               mo[2] = Fold<0x17F, 8>::ev(tp, cc, ss);
        tp = tabs + 832;               mo[3] = Fold<0x2BF, 8>::ev(tp, cc, ss);
        tp = tabs + 1088;              mo[4] = Fold<0x15F, 7>::ev(tp, cc, ss);
        tp = tabs + 1216;              mo[5] = Fold<0x2AF, 7>::ev(tp, cc, ss);
    }
}

// ---------------- K3: fused FFN, 64 rows/block, 16 chunks of 64 f ----------------
// GEMM1 exactness: A slots = [hh x10 | hh x10 | ll x10 | 0 0], B slots = [hi x10 | lo x10 | hi x10 | 0 0]
// -> dot = hh*hi + hh*lo + ll*hi = (m)*(w1) - ll*lo (error ~1e-5)
__global__ __launch_bounds__(512) void ffn_kernel(const float* __restrict__ meas,
                                                  const float* __restrict__ w1,
                                                  const float* __restrict__ b1,
                                                  const unsigned short* __restrict__ w2b,
                                                  const float* __restrict__ b2,
                                                  float* __restrict__ out) {
    __shared__ unsigned short w1L[1024 * 32];   // 64KB: 4 groups of 8 slots, group g at g^((f>>1)&3)
    __shared__ unsigned short w2L[2][256 * 64]; // 64KB dbuf, 16B-slot swizzle s^(col&7)
    __shared__ unsigned short hL[2][64 * 64];   // 16KB dbuf, 8B-slot swizzle q^(row&15)
    __shared__ float b1L[1024];

    const int tid = threadIdx.x;
    const int wv = tid >> 6, lane = tid & 63;
    const int l15 = lane & 15, kg = lane >> 4;
    const int row0 = blockIdx.x * 64;

    // -- prologue: w1 -> w1L (2 rows/thread, hi/lo layout), b1 -> b1L
    {
        float v[20];
        const float4* s4 = reinterpret_cast<const float4*>(w1 + tid * 20);
#pragma unroll
        for (int i = 0; i < 5; ++i) {
            float4 q = s4[i];
            v[4*i] = q.x; v[4*i+1] = q.y; v[4*i+2] = q.z; v[4*i+3] = q.w;
        }
        auto PK = [](unsigned short a, unsigned short bb) {
            return (unsigned int)a | ((unsigned int)bb << 16);
        };
#pragma unroll
        for (int h = 0; h < 2; ++h) {
            int r = tid * 2 + h;
            unsigned short hi[10], lo[10];
#pragma unroll
            for (int i = 0; i < 10; ++i) {
                float w = v[h * 10 + i];
                hi[i] = f2bf(w);
                lo[i] = f2bf(w - bf2f(hi[i]));
            }
            uint4 g0 = {PK(hi[0],hi[1]), PK(hi[2],hi[3]), PK(hi[4],hi[5]), PK(hi[6],hi[7])};
            uint4 g1 = {PK(hi[8],hi[9]), PK(lo[0],lo[1]), PK(lo[2],lo[3]), PK(lo[4],lo[5])};
            uint4 g2 = {PK(lo[6],lo[7]), PK(lo[8],lo[9]), PK(hi[0],hi[1]), PK(hi[2],hi[3])};
            uint4 g3 = {PK(hi[4],hi[5]), PK(hi[6],hi[7]), PK(hi[8],hi[9]), 0u};
            const int sw = (r >> 1) & 3;
            unsigned short* base = &w1L[r * 32];
            *reinterpret_cast<uint4*>(base + ((0 ^ sw) << 3)) = g0;
            *reinterpret_cast<uint4*>(base + ((1 ^ sw) << 3)) = g1;
            *reinterpret_cast<uint4*>(base + ((2 ^ sw) << 3)) = g2;
            *reinterpret_cast<uint4*>(base + ((3 ^ sw) << 3)) = g3;
        }
        b1L[tid] = b1[tid];
        b1L[tid + 512] = b1[tid + 512];
    }

    // -- prologue: meas A-fragment, hi/lo split over K=32 slots
    bf16x8 fa;
    {
        int arow = row0 + (wv & 3) * 16 + l15;
        unsigned short hh[10], ll[10];
#pragma unroll
        for (int i = 0; i < 10; ++i) {
            float m = meas[arow * 10 + i];
            hh[i] = f2bf(m);
            ll[i] = f2bf(m - bf2f(hh[i]));
        }
        short z = 0;
        if (kg == 0)      fa = bf16x8{(short)hh[0],(short)hh[1],(short)hh[2],(short)hh[3],
                                      (short)hh[4],(short)hh[5],(short)hh[6],(short)hh[7]};
        else if (kg == 1) fa = bf16x8{(short)hh[8],(short)hh[9],(short)hh[0],(short)hh[1],
                                      (short)hh[2],(short)hh[3],(short)hh[4],(short)hh[5]};
        else if (kg == 2) fa = bf16x8{(short)hh[6],(short)hh[7],(short)hh[8],(short)hh[9],
                                      (short)ll[0],(short)ll[1],(short)ll[2],(short)ll[3]};
        else              fa = bf16x8{(short)ll[4],(short)ll[5],(short)ll[6],(short)ll[7],
                                      (short)ll[8],(short)ll[9],z,z};
    }

    auto STAGE = [&](int c, int buf) {    // 32KB w2 chunk via global_load_lds, pre-swizzled src
#pragma unroll
        for (int r = 0; r < 4; ++r) {
            int col0 = r * 64 + wv * 8;                 // wave-uniform
            int col  = col0 + (lane >> 3);
            int gs   = (lane & 7) ^ (col & 7);          // fetch swizzled k-slot
            const unsigned short* src = w2b + col * 1024 + c * 64 + gs * 8;
            unsigned short* dst = (unsigned short*)w2L + buf * (256 * 64) + col0 * 64;
            __builtin_amdgcn_global_load_lds(
                (const __attribute__((address_space(1))) unsigned int*)src,
                (__attribute__((address_space(3))) unsigned int*)dst, 16, 0, 0);
        }
    };
    STAGE(0, 0);

    asm volatile("s_waitcnt lgkmcnt(0)" ::: "memory");
    asm volatile("s_waitcnt vmcnt(0)" ::: "memory");
    __builtin_amdgcn_s_barrier();

    f32x4 acc[2][4];
#pragma unroll
    for (int i = 0; i < 2; ++i)
#pragma unroll
        for (int j = 0; j < 4; ++j) acc[i][j] = f32x4{0.f, 0.f, 0.f, 0.f};

    const int wrow = wv >> 2, wcol = wv & 3;

    for (int c = 0; c < 16; ++c) {
        const int cur = c & 1;
        // ---- P1: GEMM1 h-chunk (64x64) -> hL[cur]
#pragma unroll
        for (int half = 0; half < 2; ++half) {
            int ct = (wv >> 2) * 2 + half;
            int f  = c * 64 + ct * 16 + l15;
            bf16x8 fb = *reinterpret_cast<const bf16x8*>(
                &w1L[f * 32 + ((kg ^ ((f >> 1) & 3)) << 3)]);
            f32x4 d = __builtin_amdgcn_mfma_f32_16x16x32_bf16(fa, fb, f32x4{0.f,0.f,0.f,0.f}, 0, 0, 0);
            float bb = b1L[f];
            int fl = ct * 16 + l15;
            int q = fl >> 2, f3 = fl & 3;
#pragma unroll
            for (int i = 0; i < 4; ++i) {
                int hr = (wv & 3) * 16 + kg * 4 + i;
                float hv = fmaxf(d[i] + bb, 0.f);
                hL[cur][hr * 64 + ((q ^ (hr & 15)) << 2) + f3] = f2bf(hv);
            }
        }
        asm volatile("s_waitcnt lgkmcnt(0)" ::: "memory");
        asm volatile("s_waitcnt vmcnt(0)" ::: "memory");   // my staged loads for chunk c done
        __builtin_amdgcn_s_barrier();                      // publish hL[cur] + w2L[cur]

        // ---- P2: issue next stage, then GEMM2 partial
        if (c < 15) STAGE(c + 1, cur ^ 1);
        __builtin_amdgcn_sched_barrier(0);

        bf16x8 A[2][2];
#pragma unroll
        for (int rt = 0; rt < 2; ++rt)
#pragma unroll
            for (int ks = 0; ks < 2; ++ks) {
                int r = wrow * 32 + rt * 16 + l15;
                int q0 = ks * 8 + kg * 2;
                uint2 u0 = *reinterpret_cast<const uint2*>(&hL[cur][r * 64 + ((q0 ^ (r & 15)) << 2)]);
                uint2 u1 = *reinterpret_cast<const uint2*>(&hL[cur][r * 64 + (((q0 + 1) ^ (r & 15)) << 2)]);
                union { uint2 uu[2]; bf16x8 vv; } tmp;
                tmp.uu[0] = u0; tmp.uu[1] = u1;
                A[rt][ks] = tmp.vv;
            }
#pragma unroll
        for (int ks = 0; ks < 2; ++ks)
#pragma unroll
            for (int j = 0; j < 4; ++j) {
                int col = wcol * 64 + j * 16 + l15;
                bf16x8 B = *reinterpret_cast<const bf16x8*>(
                    &w2L[cur][col * 64 + (((ks * 4 + kg) ^ (col & 7)) << 3)]);
#pragma unroll
                for (int rt = 0; rt < 2; ++rt)
                    acc[rt][j] = __builtin_amdgcn_mfma_f32_16x16x32_bf16(A[rt][ks], B, acc[rt][j], 0, 0, 0);
            }
    }

    // ---- epilogue
#pragma unroll
    for (int rt = 0; rt < 2; ++rt)
#pragma unroll
        for (int j = 0; j < 4; ++j) {
            int col = wcol * 64 + j * 16 + l15;
            float bb = b2[col];
            int rbase = row0 + wrow * 32 + rt * 16 + kg * 4;
#pragma unroll
            for (int i = 0; i < 4; ++i)
                out[(rbase + i) * EMB + col] = acc[rt][j][i] + bb;
        }
}

extern "C" void kernel_launch(void* const* d_in, const int* in_sizes, int n_in,
                              void* d_out, int out_size, void* d_ws, size_t ws_size,
                              hipStream_t stream) {
    const float* x  = (const float*)d_in[0];
    const float* qp = (const float*)d_in[1];
    const float* w1 = (const float*)d_in[2];
    const float* b1 = (const float*)d_in[3];
    const float* w2 = (const float*)d_in[4];
    const float* b2 = (const float*)d_in[5];
    float* out = (float*)d_out;

    float*          meas = (float*)d_ws;                                   // 655,360 B
    unsigned short* w2b  = (unsigned short*)((char*)d_ws + (1 << 20));     // 524,288 B
    float*          tabs = (float*)((char*)d_ws + (1 << 20) + 524288);     //   6,144 B

    hipLaunchKernelGGL(cvt_w2_kernel, dim3(256), dim3(256), 0, stream, w2, w2b);
    hipLaunchKernelGGL(qtab_kernel, dim3(1), dim3(1024), 0, stream, qp, tabs);
    hipLaunchKernelGGL(qpoly_kernel, dim3(NROWS / 64), dim3(128), 0, stream, x, qp, tabs, meas);
    hipLaunchKernelGGL(ffn_kernel, dim3(NROWS / 64), dim3(512), 0, stream,
                       meas, w1, b1, w2b, b2, out);
}